// Round 15
// baseline (117.088 us; speedup 1.0000x reference)
//
#include <hip/hip_runtime.h>
#include <cstdint>
#include <cmath>

// Problem constants (T=1024, HID=7168, R=1536, H=64, D=128, RD=64, TOPK=512)
#define NT 1024
#define NHID 7168
#define NR 1536
#define NH 64
#define ND 128
#define NTOPK 512
#define TTILE 4
#define KSPLIT 16

typedef float f32x4 __attribute__((ext_vector_type(4)));
typedef long lx2 __attribute__((ext_vector_type(2)));

__device__ __forceinline__ ushort f2bf(float x) {  // RNE f32->bf16
  uint32_t u = __float_as_uint(x);
  u += 0x7fffu + ((u >> 16) & 1u);
  return (ushort)(u >> 16);
}
__device__ __forceinline__ float bf2f(ushort u) {
  return __uint_as_float(((uint32_t)u) << 16);
}
__device__ __forceinline__ void gload_lds16(const void* g, void* l) {
  __builtin_amdgcn_global_load_lds(
      (const __attribute__((address_space(1))) uint32_t*)g,
      (__attribute__((address_space(3))) uint32_t*)l, 16, 0, 0);
}
__device__ __forceinline__ uint32_t pk_fp8x4(float a, float b, float c, float d) {
  uint32_t lo = (uint32_t)__builtin_amdgcn_cvt_pk_fp8_f32(a, b, 0, false) & 0xffffu;
  uint32_t hi = (uint32_t)__builtin_amdgcn_cvt_pk_fp8_f32(c, d, 0, false) << 16;
  return lo | hi;
}

// kk-interleaved GLOBAL layout (r12): within each 64B K-block, byte k
// (kk=k>>5, lg=(k>>3)&3, b=k&7) lives at lg*16 + kk*8 + b, so granule g
// holds the (kk0,kk1) fragment pair for lg=g (one ds_read_b128 -> 2 frags).
// LDS swizzle (r14): slot_phys = lg ^ ((row>>1)&3) -> per 16-lane read phase
// every bank serves exactly 2 dwords (minimum; conflict-free).
// Schedule (r15): depth-2 counted-vmcnt pipeline at r14 geometry -- the gate
// waits on stage(t), which was issued a FULL iteration earlier (r11-verified
// correctness; r6's bug was gating the just-issued stage(t+1)).

// ---------------------------------------------------------- rope+fwht+quant
// One wave per 128-elem row: lane l owns elements l and l+64.
__device__ __forceinline__ void rope_fwht_quant(
    float v0, float v1, int l, int pos_t,
    const float* __restrict__ cost, const float* __restrict__ sint,
    uint8_t* __restrict__ out_bytes, float* __restrict__ out_scale) {
  float a = __shfl(v0, (2 * l) & 63, 64);      // x[2i]
  float b = __shfl(v0, (2 * l + 1) & 63, 64);  // x[2i+1]
  int fi = l & 31;
  float c = cost[pos_t * 32 + fi];
  float sn = sint[pos_t * 32 + fi];
  float r;
  if (l < 32)
    r = __fsub_rn(__fmul_rn(a, c), __fmul_rn(b, sn));
  else
    r = __fadd_rn(__fmul_rn(b, c), __fmul_rn(a, sn));
  v0 = r;  // elements 64..127 untouched by rope

#pragma unroll
  for (int m = 1; m < 64; m <<= 1) {  // FWHT Sylvester order
    float p0 = __shfl_xor(v0, m, 64);
    float p1 = __shfl_xor(v1, m, 64);
    bool up = (l & m) == 0;
    v0 = up ? __fadd_rn(v0, p0) : __fsub_rn(p0, v0);
    v1 = up ? __fadd_rn(v1, p1) : __fsub_rn(p1, v1);
  }
  {  // m = 64: pair (l, l+64) lane-local
    float A0 = v0, B0 = v1;
    v0 = __fadd_rn(A0, B0);
    v1 = __fsub_rn(A0, B0);
  }
  const float WS = 0.08838834764831843f;  // 128^-0.5
  v0 = __fmul_rn(v0, WS);
  v1 = __fmul_rn(v1, WS);

  float am = fmaxf(fabsf(v0), fabsf(v1));
#pragma unroll
  for (int m = 1; m < 64; m <<= 1) am = fmaxf(am, __shfl_xor(am, m, 64));
  am = fmaxf(am, 1e-4f);
  float ratio = __fdiv_rn(am, 448.0f);
  // exact ceil(log2(ratio)) via mantissa carry (UE8M0)
  uint32_t rb = __float_as_uint(ratio);
  int e = (int)((rb + 0x7fffffu) >> 23) - 127;
  float sf = __uint_as_float((uint32_t)(e + 127) << 23);
  float inv = __uint_as_float((uint32_t)(127 - e) << 23);
  float q0 = __fmul_rn(v0, inv);
  float q1 = __fmul_rn(v1, inv);
  int b0 = __builtin_amdgcn_cvt_pk_fp8_f32(q0, q0, 0, false);
  int b1 = __builtin_amdgcn_cvt_pk_fp8_f32(q1, q1, 0, false);
  out_bytes[l] = (uint8_t)(b0 & 0xff);
  out_bytes[l + 64] = (uint8_t)(b1 & 0xff);
  if (l == 0) *out_scale = sf;
}

// --------------------- prep: rope table + all fp8 casts/transposes (1 launch)
// Blocks [0,3584): hidden cast (+rope table in [0,1024));
// [3584,4352): q_lora cast; [4352,4688): wk/w_proj transpose-cast (x64);
// [4688,7760): wq_b transpose-cast. All outputs kk-interleaved.
__global__ __launch_bounds__(256)
void prep_all_k(const float* __restrict__ hidden, const float* __restrict__ q_lora,
                const float* __restrict__ wk, const float* __restrict__ wp,
                const float* __restrict__ wq_b, const int* __restrict__ pos,
                uint32_t* __restrict__ hidden8, uint32_t* __restrict__ qlora8,
                uint8_t* __restrict__ wkp8, uint8_t* __restrict__ wqb8,
                float* __restrict__ cost, float* __restrict__ sint) {
  __shared__ uint8_t t8[64][68];
  int bid = blockIdx.x, tid = threadIdx.x;
  if (bid < 4352) {
    // ---- linear casts, 8 f32 -> one permuted 8B group
    bool isq = bid >= 3584;
    size_t i = (size_t)(isq ? bid - 3584 : bid) * 256 + tid;
    const float* src = isq ? q_lora : hidden;
    uint32_t* dst = isq ? qlora8 : hidden8;
    const f32x4* pp = (const f32x4*)(src + i * 8);
    f32x4 a = pp[0], b = pp[1];
    size_t blk = i >> 3;
    int j = (int)(i & 7);
    size_t dw = blk * 16 + (size_t)((j & 3) * 4 + (j >> 2) * 2);
    dst[dw] = pk_fp8x4(a[0], a[1], a[2], a[3]);
    dst[dw + 1] = pk_fp8x4(b[0], b[1], b[2], b[3]);
    if (bid < NT && tid < 32) {
      int t = bid, ii = tid;
      double x = (double)(2 * ii) / 64.0;
      double pw = pow(10000.0, x);
      float p32 = (float)pw;
      float invf = __fdiv_rn(1.0f, p32);
      float ang = __fmul_rn((float)pos[t], invf);
      cost[t * 32 + ii] = (float)cos((double)ang);
      sint[t * 32 + ii] = (float)sin((double)ang);
    }
    return;
  }
  // ---- transpose-cast: in [K][N_] f32 -> out [N_row][Kdim] e4m3 interleaved
  const float* in;
  uint8_t* out;
  int N_, n0, orow0, Kdim, k0;
  float scale;
  if (bid < 4688) {
    int local = bid - 4352;
    int bx = local % 3, by = local / 3;
    in = (bx < 2) ? wk : wp;
    N_ = (bx < 2) ? ND : NH;
    n0 = (bx < 2) ? bx * 64 : 0;
    orow0 = (bx < 2) ? bx * 64 : 128;
    Kdim = NHID;
    k0 = by * 64;
    out = wkp8;
    scale = 64.0f;
  } else {
    int local = bid - 4688;
    int nx = local % 128, ky = local / 128;
    in = wq_b;
    N_ = NH * ND;
    n0 = nx * 64;
    orow0 = n0;
    Kdim = NR;
    k0 = ky * 64;
    out = wqb8;
    scale = 1.0f;
  }
  int r = tid >> 4, c = (tid & 15) * 4;
#pragma unroll
  for (int rr = 0; rr < 64; rr += 16) {
    f32x4 v = *(const f32x4*)(in + (size_t)(k0 + rr + r) * N_ + n0 + c);
    *(uint32_t*)&t8[rr + r][c] =
        pk_fp8x4(v[0] * scale, v[1] * scale, v[2] * scale, v[3] * scale);
  }
  __syncthreads();
  int sp = ((c >> 3) & 3) * 16 + (c >> 5) * 8 + ((c >> 2) & 1) * 4;  // kk-perm
#pragma unroll
  for (int rr = 0; rr < 64; rr += 16) {
    int orow = rr + r;
    uint32_t w = (uint32_t)t8[c + 0][orow] | ((uint32_t)t8[c + 1][orow] << 8) |
                 ((uint32_t)t8[c + 2][orow] << 16) | ((uint32_t)t8[c + 3][orow] << 24);
    *(uint32_t*)(out + (size_t)(orow0 + orow) * Kdim + k0 + sp) = w;
  }
}

// ------------------- fp8 GEMM (r14 geometry, depth-2 counted-vmcnt pipeline)
// 4 waves (2x2), wave tile (BM/2)x(BN/2), BK=64, dbuf. Schedule:
//   prologue: stage(0); stage(1)
//   iter t:   vmcnt(LPS) [drains stage(t), issued a FULL iter earlier;
//             leaves stage(t+1)'s LPS loads in flight]
//             s_barrier; compute(buf t&1); s_barrier; stage(t+2 -> buf t&1)
//   last iter: vmcnt(0). No sched_barrier (m141/r6 lesson).
// LDS slot swizzle lg^((row>>1)&3): per-phase bank load exactly 2 dwords.
// FUSEQ: BN=128 block column = one head; epilogue = bf16 tile in padded LDS
// overlay + rope/FWHT/quant. Else: f32 partials C[z*M*N + m*N + n].
template <int BM, int BN, bool FUSEQ>
__global__ __launch_bounds__(256)
void gemm_fp8_k(const uint8_t* __restrict__ A, const uint8_t* __restrict__ Bt,
                float* __restrict__ C, const float* __restrict__ cost,
                const float* __restrict__ sint, uint8_t* __restrict__ qfp8,
                float* __restrict__ qscale, int M, int N, int K, int kchunk) {
  constexpr int FM = BM / 32;
  constexpr int FN = BN / 32;
  constexpr int ABYTES = BM * 64;
  constexpr int BBYTES = BN * 64;
  constexpr int BUF = ABYTES + BBYTES;
  constexpr int LPS = BM / 64 + BN / 64;  // gload_lds instrs per stage/thread
  constexpr int OVER = FUSEQ ? BM * 132 * 2 : 0;
  constexpr int SMEM = (OVER > 2 * BUF) ? OVER : 2 * BUF;
  __shared__ char smem[SMEM];
  int tid = threadIdx.x;
  int wave = tid >> 6, lane = tid & 63;
  int ln = lane & 15, lg = lane >> 4;
  int n0 = blockIdx.x * BN, m0 = blockIdx.y * BM;
  int k0 = blockIdx.z * kchunk;
  int wm = (wave >> 1) * (BM / 2), wn = (wave & 1) * (BN / 2);

  f32x4 acc[FM][FN];
#pragma unroll
  for (int m = 0; m < FM; m++)
#pragma unroll
    for (int n = 0; n < FN; n++) acc[m][n] = {0.f, 0.f, 0.f, 0.f};

  auto stage = [&](int buf, int kk0) {
    char* base = smem + buf * BUF;
#pragma unroll
    for (int c = 0; c < BM / 64; c++) {  // A: BM rows x 64B, swizzled src
      int o = c * 256 + tid;
      int row = o >> 2, gd = o & 3;
      int gs = gd ^ ((row >> 1) & 3);
      gload_lds16(A + (size_t)(m0 + row) * K + kk0 + gs * 16, base + o * 16);
    }
#pragma unroll
    for (int c = 0; c < BN / 64; c++) {  // B: BN rows x 64B, swizzled src
      int o = c * 256 + tid;
      int row = o >> 2, gd = o & 3;
      int gs = gd ^ ((row >> 1) & 3);
      gload_lds16(Bt + (size_t)(n0 + row) * K + kk0 + gs * 16,
                  base + ABYTES + o * 16);
    }
  };

  int ntile = kchunk / 64;  // >= 7 in all uses
  stage(0, k0);
  stage(1, k0 + 64);
  int cur = 0;
  for (int t = 0; t < ntile; t++) {
    if (t + 1 < ntile) {
      if constexpr (LPS == 3)
        asm volatile("s_waitcnt vmcnt(3)" ::: "memory");
      else
        asm volatile("s_waitcnt vmcnt(2)" ::: "memory");
    } else {
      asm volatile("s_waitcnt vmcnt(0)" ::: "memory");
    }
    __builtin_amdgcn_s_barrier();
    const uint8_t* ap = (const uint8_t*)smem + cur * BUF;
    const uint8_t* bp = ap + ABYTES;
    lx2 av[FM], bv[FN];
#pragma unroll
    for (int m = 0; m < FM; m++) {
      int row = wm + m * 16 + ln;
      av[m] = *(const lx2*)(ap + row * 64 + ((lg ^ ((row >> 1) & 3)) << 4));
    }
#pragma unroll
    for (int n = 0; n < FN; n++) {
      int row = wn + n * 16 + ln;
      bv[n] = *(const lx2*)(bp + row * 64 + ((lg ^ ((row >> 1) & 3)) << 4));
    }
#pragma unroll
    for (int m = 0; m < FM; m++)
#pragma unroll
      for (int n = 0; n < FN; n++)
        acc[m][n] = __builtin_amdgcn_mfma_f32_16x16x32_fp8_fp8(
            av[m][0], bv[n][0], acc[m][n], 0, 0, 0);
#pragma unroll
    for (int m = 0; m < FM; m++)
#pragma unroll
      for (int n = 0; n < FN; n++)
        acc[m][n] = __builtin_amdgcn_mfma_f32_16x16x32_fp8_fp8(
            av[m][1], bv[n][1], acc[m][n], 0, 0, 0);
    __builtin_amdgcn_s_barrier();
    if (t + 2 < ntile) stage(cur, k0 + (t + 2) * 64);
    cur ^= 1;
  }

  if constexpr (FUSEQ) {
    // ---- epilogue: bf16 tile + rope/FWHT/quant (padded overlay, ~free banks)
    ushort(*qtile)[132] = (ushort(*)[132])smem;
#pragma unroll
    for (int m = 0; m < FM; m++)
#pragma unroll
      for (int n = 0; n < FN; n++)
#pragma unroll
        for (int j = 0; j < 4; j++)
          qtile[wm + m * 16 + lg * 4 + j][wn + n * 16 + ln] = f2bf(acc[m][n][j]);
    __syncthreads();
    int h = blockIdx.x;  // N=8192, BN=128: one head per block column
    for (int r = 0; r < BM / 4; r++) {
      int row = wave * (BM / 4) + r;
      int tq = m0 + row;
      float v0 = bf2f(qtile[row][lane]);
      float v1 = bf2f(qtile[row][64 + lane]);
      rope_fwht_quant(v0, v1, lane, tq, cost, sint,
                      qfp8 + ((size_t)tq * NH + h) * ND,
                      qscale + (size_t)tq * NH + h);
    }
  } else {
    float* Cz = C + (size_t)blockIdx.z * M * N;
#pragma unroll
    for (int m = 0; m < FM; m++)
#pragma unroll
      for (int n = 0; n < FN; n++)
#pragma unroll
        for (int j = 0; j < 4; j++) {
          int row = m0 + wm + m * 16 + lg * 4 + j;
          int col = n0 + wn + n * 16 + ln;
          Cz[(size_t)row * N + col] = acc[m][n][j];
        }
  }
}

// ----------------------------------------------- k finalize + weights (merged)
// kpart: [KSPLIT][NT][192] f32 = 64*(hidden @ [wk|w_proj]) partials.
// LN is scale-invariant (x64 cancels); weights compensated by 0.125/64.
// Must run AFTER the fused q GEMM (needs qscale).
__global__ __launch_bounds__(256)
void kfin_weights_k(const float* __restrict__ kpart, const float* __restrict__ gamma,
                    const float* __restrict__ beta, const float* __restrict__ cost,
                    const float* __restrict__ sint, const float* __restrict__ qscale,
                    uint8_t* __restrict__ kfp8, float* __restrict__ kscale,
                    float* __restrict__ weights) {
  int l = threadIdx.x & 63;
  int row = blockIdx.x * 4 + (threadIdx.x >> 6);  // t
  float v0 = 0.0f, v1 = 0.0f, ws = 0.0f;
#pragma unroll
  for (int p = 0; p < KSPLIT; p++) {
    const float* base = kpart + (size_t)p * (NT * 192) + row * 192;
    v0 = __fadd_rn(v0, base[l]);
    v1 = __fadd_rn(v1, base[l + 64]);
    ws = __fadd_rn(ws, base[128 + l]);
  }
  // weights: * H^-0.5(=0.125) * (1/64 fp8-scale comp) * qscale * SM_SCALE
  float w = __fmul_rn(ws, 0.001953125f);
  w = __fmul_rn(w, qscale[row * NH + l]);
  w = __fmul_rn(w, 0.08838834764831843f);
  weights[row * NH + l] = w;
  // layernorm over 128
  float s = __fadd_rn(v0, v1);
#pragma unroll
  for (int m = 1; m < 64; m <<= 1) s = __fadd_rn(s, __shfl_xor(s, m, 64));
  float mu = __fmul_rn(s, 0.0078125f);
  float d0 = __fsub_rn(v0, mu), d1 = __fsub_rn(v1, mu);
  float vs = __fadd_rn(__fmul_rn(d0, d0), __fmul_rn(d1, d1));
#pragma unroll
  for (int m = 1; m < 64; m <<= 1) vs = __fadd_rn(vs, __shfl_xor(vs, m, 64));
  float var = __fmul_rn(vs, 0.0078125f);
  float rs = (float)(1.0 / sqrt((double)__fadd_rn(var, 1e-5f)));
  v0 = __fadd_rn(__fmul_rn(__fmul_rn(d0, rs), gamma[l]), beta[l]);
  v1 = __fadd_rn(__fmul_rn(__fmul_rn(d1, rs), gamma[l + 64]), beta[l + 64]);
  rope_fwht_quant(v0, v1, l, row, cost, sint, kfp8 + (size_t)row * ND, kscale + row);
}

// ------------------------------------------------------------------- scores
// Block = (4-t tile, 128-s chunk); grid 1152. Q+K staged in LDS via
// global_load_lds with a 16B-granule XOR swizzle (G ^= (row>>1)&7) so that
// ds_read_b64 fragment reads are <=2-way bank-aliased (free). Wave w covers
// s in [w*32, w*32+32) for all 64 heads; h-sum completed in-wave -> scores
// final (kscale factored out, applied in topk; exact for pow2 scales).
__global__ __launch_bounds__(256)
void scores_k(const uint8_t* __restrict__ qfp8, const uint8_t* __restrict__ kfp8,
              const float* __restrict__ weights, float* __restrict__ scores) {
  __shared__ uint8_t q_lds[TTILE * 64 * 128];  // 32KB
  __shared__ uint8_t k_lds[128 * 128];         // 16KB
  __shared__ float w_lds[TTILE * 64];          // 1KB

  int b = blockIdx.x;
  int g = 0;  // t-tile group: tiles [32g,32g+32) have g+1 s-chunks
  while (g < 7 && b >= 16 * (g + 1) * (g + 2)) g++;
  int r = b - 16 * g * (g + 1);
  int a = 32 * g + r / (g + 1);
  int chunk = r % (g + 1);
  int t0 = a * TTILE;
  int s0 = chunk * 128;

  int tid = threadIdx.x;
  int wave = tid >> 6, lane = tid & 63;
  int lg = lane >> 4, ln = lane & 15;

  // ---- stage Q (256 rows x 128B) with inverse-swizzled source, linear dest
  const uint8_t* qbase = qfp8 + (size_t)t0 * 64 * 128;
#pragma unroll
  for (int it = 0; it < 8; it++) {
    int o = it * 256 + wave * 64 + lane;  // 16B-granule index
    int row = o >> 3, G = o & 7;
    int src = row * 128 + ((G ^ ((row >> 1) & 7)) << 4);
    gload_lds16(qbase + src, q_lds + (it * 256 + wave * 64) * 16);
  }
  // ---- stage K (128 rows x 128B)
  const uint8_t* kbase = kfp8 + (size_t)s0 * 128;
#pragma unroll
  for (int it = 0; it < 4; it++) {
    int o = it * 256 + wave * 64 + lane;
    int row = o >> 3, G = o & 7;
    int src = row * 128 + ((G ^ ((row >> 1) & 7)) << 4);
    gload_lds16(kbase + src, k_lds + (it * 256 + wave * 64) * 16);
  }
  w_lds[tid] = weights[t0 * NH + tid];
  __syncthreads();

  // ---- K fragments: loaded once, reused for all 4 t and 4 h-tiles
  long bfr[2][4];
#pragma unroll
  for (int sj = 0; sj < 2; sj++) {
    int srow = wave * 32 + sj * 16 + ln;
    int base = srow * 128;
    int xr = ((srow >> 1) & 7) << 4;
#pragma unroll
    for (int ks = 0; ks < 4; ks++)
      bfr[sj][ks] = *(const long*)(k_lds + base + ((ks * 32 + lg * 8) ^ xr));
  }

  float p[TTILE][2];
#pragma unroll
  for (int tt = 0; tt < TTILE; tt++) p[tt][0] = p[tt][1] = 0.0f;

#pragma unroll
  for (int ht = 0; ht < 4; ht++) {  // head tiles of 16
    long afr[TTILE][4];
#pragma unroll
    for (int tt = 0; tt < TTILE; tt++) {
      int qrow = tt * 64 + ht * 16 + ln;
      int base = qrow * 128;
      int xr = ((qrow >> 1) & 7) << 4;
#pragma unroll
      for (int ks = 0; ks < 4; ks++)
        afr[tt][ks] = *(const long*)(q_lds + base + ((ks * 32 + lg * 8) ^ xr));
    }
#pragma unroll
    for (int tt = 0; tt < TTILE; tt++) {
      float wj[4];
#pragma unroll
      for (int j = 0; j < 4; j++) wj[j] = w_lds[tt * 64 + ht * 16 + lg * 4 + j];
#pragma unroll
      for (int sj = 0; sj < 2; sj++) {
        f32x4 acc = {0.f, 0.f, 0.f, 0.f};
#pragma unroll
        for (int ks = 0; ks < 4; ks++)
          acc = __builtin_amdgcn_mfma_f32_16x16x32_fp8_fp8(afr[tt][ks], bfr[sj][ks],
                                                           acc, 0, 0, 0);
#pragma unroll
        for (int j = 0; j < 4; j++)
          p[tt][sj] = fmaf(wj[j], fmaxf(acc[j], 0.0f), p[tt][sj]);
      }
    }
  }

#pragma unroll
  for (int tt = 0; tt < TTILE; tt++)
#pragma unroll
    for (int sj = 0; sj < 2; sj++) {
      float v = p[tt][sj];
      v += __shfl_xor(v, 16, 64);
      v += __shfl_xor(v, 32, 64);
      if (lg == 0)
        scores[(size_t)(t0 + tt) * NT + s0 + wave * 32 + sj * 16 + ln] = v;
    }
}

// -------------------------------------------------------------------- top-k
__global__ __launch_bounds__(256)
void topk_k(const float* __restrict__ scores, const float* __restrict__ kscale,
            float* __restrict__ outv, float* __restrict__ outi) {
  __shared__ unsigned long long key[1024];
  int t = blockIdx.x, tid = threadIdx.x;
#pragma unroll
  for (int p = 0; p < 4; p++) {
    int s = tid + p * 256;
    float v;
    if (s <= t) {
      v = __fmul_rn(scores[(size_t)t * NT + s], kscale[s]);  // exact pow2 factor
    } else {
      v = -1e30f;
    }
    unsigned u = __float_as_uint(v);
    unsigned ou = (u & 0x80000000u) ? ~u : (u | 0x80000000u);
    key[s] = ((unsigned long long)ou << 32) | (unsigned)(~(unsigned)s);
  }
  for (int k = 2; k <= 1024; k <<= 1) {
    for (int j = k >> 1; j > 0; j >>= 1) {
      __syncthreads();
#pragma unroll
      for (int p = 0; p < 2; p++) {
        int i = tid + p * 256;
        int l = ((i & ~(j - 1)) << 1) | (i & (j - 1));
        int m = l + j;
        bool desc = ((l & k) == 0);
        unsigned long long a = key[l], b = key[m];
        if (desc ? (a < b) : (a > b)) {
          key[l] = b;
          key[m] = a;
        }
      }
    }
  }
  __syncthreads();
#pragma unroll
  for (int p = 0; p < 2; p++) {
    int r = tid + p * 256;
    unsigned long long kk = key[r];
    unsigned ou = (unsigned)(kk >> 32);
    unsigned u = (ou & 0x80000000u) ? (ou ^ 0x80000000u) : ~ou;
    unsigned idx = (~(unsigned)(kk & 0xffffffffu)) & 1023u;
    outv[(size_t)t * NTOPK + r] = __uint_as_float(u);
    outi[(size_t)t * NTOPK + r] = (float)idx;
  }
}

// ------------------------------------------------------------------- launch
extern "C" void kernel_launch(void* const* d_in, const int* in_sizes, int n_in,
                              void* d_out, int out_size, void* d_ws, size_t ws_size,
                              hipStream_t stream) {
  const float* hidden = (const float*)d_in[0];
  const float* q_lora = (const float*)d_in[1];
  const int* positions = (const int*)d_in[2];
  const float* wq_b = (const float*)d_in[3];
  const float* wk = (const float*)d_in[4];
  const float* w_proj = (const float*)d_in[5];
  const float* ln_g = (const float*)d_in[6];
  const float* ln_b = (const float*)d_in[7];
  float* out = (float*)d_out;

  // ---- workspace layout (all fp8 operands coexist; scores aliases hidden8)
  char* u0 = (char*)d_ws;
  uint8_t* hidden8 = (uint8_t*)u0;                     //  7,340,032 B
  uint8_t* wkp8 = (uint8_t*)(u0 + 7340032);            //  1,376,256 B
  uint8_t* wqb8 = (uint8_t*)(u0 + 8716288);            // 12,582,912 B
  uint8_t* qlora8 = (uint8_t*)(u0 + 21299200);         //  1,572,864 B
  float* scores = (float*)u0;  // 4,194,304 B; hidden8 dead before scores_k
  char* p = u0 + 22872064;
  float* kpart = (float*)p;    p += 12582912;          // [16][1024][192] f32
  float* cost = (float*)p;     p += 131072;
  float* sint = (float*)p;     p += 131072;
  float* kscale = (float*)p;   p += 4096;
  float* qscale = (float*)p;   p += 262144;
  float* weights = (float*)p;  p += 262144;
  uint8_t* kfp8 = (uint8_t*)p; p += 131072;
  uint8_t* qfp8 = (uint8_t*)p; p += 8388608;

  // 1) all casts + rope table (kk-interleaved fp8 outputs)
  prep_all_k<<<7760, 256, 0, stream>>>(hidden, q_lora, wk, w_proj, wq_b,
                                       positions, (uint32_t*)hidden8,
                                       (uint32_t*)qlora8, wkp8, wqb8,
                                       cost, sint);

  // 2) k + weights projections (B = [wk|w_proj] x64; LN scale-invariant,
  //    weights compensated by 1/64 in kfin_weights_k). 7 iters/chunk.
  gemm_fp8_k<64, 64, false><<<dim3(3, 16, KSPLIT), 256, 0, stream>>>(
      hidden8, wkp8, kpart, nullptr, nullptr, nullptr, nullptr,
      NT, 192, NHID, NHID / KSPLIT);

  // 3) q projection with fused rope/FWHT/quant epilogue (24 iters)
  gemm_fp8_k<64, 128, true><<<dim3(64, 16, 1), 256, 0, stream>>>(
      qlora8, wqb8, nullptr, cost, sint, qfp8, qscale,
      NT, NH * ND, NR, NR);

  // 4) k finalize + weights
  kfin_weights_k<<<NT / 4, 256, 0, stream>>>(kpart, ln_g, ln_b, cost, sint,
                                             qscale, kfp8, kscale, weights);

  // 5) scores + 6) top-k
  scores_k<<<1152, 256, 0, stream>>>(qfp8, kfp8, weights, scores);
  topk_k<<<NT, 256, 0, stream>>>(scores, kscale, out, out + (size_t)NT * NTOPK);
}

// Round 16
// 115.316 us; speedup vs baseline: 1.0154x; 1.0154x over previous
//
#include <hip/hip_runtime.h>
#include <cstdint>
#include <cmath>

// Problem constants (T=1024, HID=7168, R=1536, H=64, D=128, RD=64, TOPK=512)
#define NT 1024
#define NHID 7168
#define NR 1536
#define NH 64
#define ND 128
#define NTOPK 512
#define TTILE 4
#define KSPLIT 16

typedef float f32x4 __attribute__((ext_vector_type(4)));
typedef long lx2 __attribute__((ext_vector_type(2)));

__device__ __forceinline__ ushort f2bf(float x) {  // RNE f32->bf16
  uint32_t u = __float_as_uint(x);
  u += 0x7fffu + ((u >> 16) & 1u);
  return (ushort)(u >> 16);
}
__device__ __forceinline__ float bf2f(ushort u) {
  return __uint_as_float(((uint32_t)u) << 16);
}
__device__ __forceinline__ void gload_lds16(const void* g, void* l) {
  __builtin_amdgcn_global_load_lds(
      (const __attribute__((address_space(1))) uint32_t*)g,
      (__attribute__((address_space(3))) uint32_t*)l, 16, 0, 0);
}
__device__ __forceinline__ uint32_t pk_fp8x4(float a, float b, float c, float d) {
  uint32_t lo = (uint32_t)__builtin_amdgcn_cvt_pk_fp8_f32(a, b, 0, false) & 0xffffu;
  uint32_t hi = (uint32_t)__builtin_amdgcn_cvt_pk_fp8_f32(c, d, 0, false) << 16;
  return lo | hi;
}

// kk-interleaved GLOBAL layout (r12): within each 64B K-block, byte k
// (kk=k>>5, lg=(k>>3)&3, b=k&7) lives at lg*16 + kk*8 + b, so granule g
// holds the (kk0,kk1) fragment pair for lg=g (one ds_read_b128 -> 2 frags).
// LDS swizzle (r14): slot_phys = lg ^ ((row>>1)&3) -> per 16-lane read phase
// every bank serves exactly 2 dwords (minimum; conflict-free; verified r14:
// SQ_LDS_BANK_CONFLICT 2.6M -> 262K).
// r16: NTILE constexpr, loop unrolled x2 with STATIC buffer indices (buf*BUF
// folds into ds_read offset: immediates) + hoisted stage pointers (+64/iter)
// -> kills the ~80 VALU ops/iter of per-iteration address recompute.

// ---------------------------------------------------------- rope+fwht+quant
// One wave per 128-elem row: lane l owns elements l and l+64.
__device__ __forceinline__ void rope_fwht_quant(
    float v0, float v1, int l, int pos_t,
    const float* __restrict__ cost, const float* __restrict__ sint,
    uint8_t* __restrict__ out_bytes, float* __restrict__ out_scale) {
  float a = __shfl(v0, (2 * l) & 63, 64);      // x[2i]
  float b = __shfl(v0, (2 * l + 1) & 63, 64);  // x[2i+1]
  int fi = l & 31;
  float c = cost[pos_t * 32 + fi];
  float sn = sint[pos_t * 32 + fi];
  float r;
  if (l < 32)
    r = __fsub_rn(__fmul_rn(a, c), __fmul_rn(b, sn));
  else
    r = __fadd_rn(__fmul_rn(b, c), __fmul_rn(a, sn));
  v0 = r;  // elements 64..127 untouched by rope

#pragma unroll
  for (int m = 1; m < 64; m <<= 1) {  // FWHT Sylvester order
    float p0 = __shfl_xor(v0, m, 64);
    float p1 = __shfl_xor(v1, m, 64);
    bool up = (l & m) == 0;
    v0 = up ? __fadd_rn(v0, p0) : __fsub_rn(p0, v0);
    v1 = up ? __fadd_rn(v1, p1) : __fsub_rn(p1, v1);
  }
  {  // m = 64: pair (l, l+64) lane-local
    float A0 = v0, B0 = v1;
    v0 = __fadd_rn(A0, B0);
    v1 = __fsub_rn(A0, B0);
  }
  const float WS = 0.08838834764831843f;  // 128^-0.5
  v0 = __fmul_rn(v0, WS);
  v1 = __fmul_rn(v1, WS);

  float am = fmaxf(fabsf(v0), fabsf(v1));
#pragma unroll
  for (int m = 1; m < 64; m <<= 1) am = fmaxf(am, __shfl_xor(am, m, 64));
  am = fmaxf(am, 1e-4f);
  float ratio = __fdiv_rn(am, 448.0f);
  // exact ceil(log2(ratio)) via mantissa carry (UE8M0)
  uint32_t rb = __float_as_uint(ratio);
  int e = (int)((rb + 0x7fffffu) >> 23) - 127;
  float sf = __uint_as_float((uint32_t)(e + 127) << 23);
  float inv = __uint_as_float((uint32_t)(127 - e) << 23);
  float q0 = __fmul_rn(v0, inv);
  float q1 = __fmul_rn(v1, inv);
  int b0 = __builtin_amdgcn_cvt_pk_fp8_f32(q0, q0, 0, false);
  int b1 = __builtin_amdgcn_cvt_pk_fp8_f32(q1, q1, 0, false);
  out_bytes[l] = (uint8_t)(b0 & 0xff);
  out_bytes[l + 64] = (uint8_t)(b1 & 0xff);
  if (l == 0) *out_scale = sf;
}

// --------------------- prep: rope table + all fp8 casts/transposes (1 launch)
// Blocks [0,3584): hidden cast (+rope table in [0,1024));
// [3584,4352): q_lora cast; [4352,4688): wk/w_proj transpose-cast (x64);
// [4688,7760): wq_b transpose-cast. All outputs kk-interleaved.
__global__ __launch_bounds__(256)
void prep_all_k(const float* __restrict__ hidden, const float* __restrict__ q_lora,
                const float* __restrict__ wk, const float* __restrict__ wp,
                const float* __restrict__ wq_b, const int* __restrict__ pos,
                uint32_t* __restrict__ hidden8, uint32_t* __restrict__ qlora8,
                uint8_t* __restrict__ wkp8, uint8_t* __restrict__ wqb8,
                float* __restrict__ cost, float* __restrict__ sint) {
  __shared__ uint8_t t8[64][68];
  int bid = blockIdx.x, tid = threadIdx.x;
  if (bid < 4352) {
    // ---- linear casts, 8 f32 -> one permuted 8B group
    bool isq = bid >= 3584;
    size_t i = (size_t)(isq ? bid - 3584 : bid) * 256 + tid;
    const float* src = isq ? q_lora : hidden;
    uint32_t* dst = isq ? qlora8 : hidden8;
    const f32x4* pp = (const f32x4*)(src + i * 8);
    f32x4 a = pp[0], b = pp[1];
    size_t blk = i >> 3;
    int j = (int)(i & 7);
    size_t dw = blk * 16 + (size_t)((j & 3) * 4 + (j >> 2) * 2);
    dst[dw] = pk_fp8x4(a[0], a[1], a[2], a[3]);
    dst[dw + 1] = pk_fp8x4(b[0], b[1], b[2], b[3]);
    if (bid < NT && tid < 32) {
      int t = bid, ii = tid;
      double x = (double)(2 * ii) / 64.0;
      double pw = pow(10000.0, x);
      float p32 = (float)pw;
      float invf = __fdiv_rn(1.0f, p32);
      float ang = __fmul_rn((float)pos[t], invf);
      cost[t * 32 + ii] = (float)cos((double)ang);
      sint[t * 32 + ii] = (float)sin((double)ang);
    }
    return;
  }
  // ---- transpose-cast: in [K][N_] f32 -> out [N_row][Kdim] e4m3 interleaved
  const float* in;
  uint8_t* out;
  int N_, n0, orow0, Kdim, k0;
  float scale;
  if (bid < 4688) {
    int local = bid - 4352;
    int bx = local % 3, by = local / 3;
    in = (bx < 2) ? wk : wp;
    N_ = (bx < 2) ? ND : NH;
    n0 = (bx < 2) ? bx * 64 : 0;
    orow0 = (bx < 2) ? bx * 64 : 128;
    Kdim = NHID;
    k0 = by * 64;
    out = wkp8;
    scale = 64.0f;
  } else {
    int local = bid - 4688;
    int nx = local % 128, ky = local / 128;
    in = wq_b;
    N_ = NH * ND;
    n0 = nx * 64;
    orow0 = n0;
    Kdim = NR;
    k0 = ky * 64;
    out = wqb8;
    scale = 1.0f;
  }
  int r = tid >> 4, c = (tid & 15) * 4;
#pragma unroll
  for (int rr = 0; rr < 64; rr += 16) {
    f32x4 v = *(const f32x4*)(in + (size_t)(k0 + rr + r) * N_ + n0 + c);
    *(uint32_t*)&t8[rr + r][c] =
        pk_fp8x4(v[0] * scale, v[1] * scale, v[2] * scale, v[3] * scale);
  }
  __syncthreads();
  int sp = ((c >> 3) & 3) * 16 + (c >> 5) * 8 + ((c >> 2) & 1) * 4;  // kk-perm
#pragma unroll
  for (int rr = 0; rr < 64; rr += 16) {
    int orow = rr + r;
    uint32_t w = (uint32_t)t8[c + 0][orow] | ((uint32_t)t8[c + 1][orow] << 8) |
                 ((uint32_t)t8[c + 2][orow] << 16) | ((uint32_t)t8[c + 3][orow] << 24);
    *(uint32_t*)(out + (size_t)(orow0 + orow) * Kdim + k0 + sp) = w;
  }
}

// ----------- fp8 GEMM (r14 2-phase schedule; static-unrolled, hoisted addrs)
// 4 waves (2x2), wave tile (BM/2)x(BN/2), BK=64, dbuf. Per-iter order is
// byte-identical to r14: stage(next) -> compute(cur) -> __syncthreads().
// r16 codegen: NTILE constexpr; loop unrolled x2 so buffer indices are
// STATIC (buf*BUF folds into ds_read offset: immediates); stage pointers
// precomputed once and bumped +64/iter. LDS slot swizzle lg^((row>>1)&3).
// FUSEQ: BN=128 block column = one head; epilogue = bf16 tile in padded LDS
// overlay + rope/FWHT/quant. Else: f32 partials C[z*M*N + m*N + n].
template <int BM, int BN, int KCHUNK, bool FUSEQ>
__global__ __launch_bounds__(256)
void gemm_fp8_k(const uint8_t* __restrict__ A, const uint8_t* __restrict__ Bt,
                float* __restrict__ C, const float* __restrict__ cost,
                const float* __restrict__ sint, uint8_t* __restrict__ qfp8,
                float* __restrict__ qscale, int M, int N, int K) {
  constexpr int FM = BM / 32;
  constexpr int FN = BN / 32;
  constexpr int ABYTES = BM * 64;
  constexpr int BBYTES = BN * 64;
  constexpr int BUF = ABYTES + BBYTES;
  constexpr int NTILE = KCHUNK / 64;
  constexpr int NA = BM / 64, NB = BN / 64;
  constexpr int OVER = FUSEQ ? BM * 132 * 2 : 0;
  constexpr int SMEM = (OVER > 2 * BUF) ? OVER : 2 * BUF;
  __shared__ char smem[SMEM];
  int tid = threadIdx.x;
  int wave = tid >> 6, lane = tid & 63;
  int ln = lane & 15, lg = lane >> 4;
  int n0 = blockIdx.x * BN, m0 = blockIdx.y * BM;
  int k0 = blockIdx.z * KCHUNK;
  int wm = (wave >> 1) * (BM / 2), wn = (wave & 1) * (BN / 2);

  f32x4 acc[FM][FN];
#pragma unroll
  for (int m = 0; m < FM; m++)
#pragma unroll
    for (int n = 0; n < FN; n++) acc[m][n] = {0.f, 0.f, 0.f, 0.f};

  // ---- hoisted stage pointers (advance +64 per staged tile)
  const uint8_t* aSrc[NA];
  char* aDst[NA];
#pragma unroll
  for (int c = 0; c < NA; c++) {
    int o = c * 256 + tid;
    int row = o >> 2, gd = o & 3;
    int gs = gd ^ ((row >> 1) & 3);
    aSrc[c] = A + (size_t)(m0 + row) * K + k0 + gs * 16;
    aDst[c] = smem + o * 16;
  }
  const uint8_t* bSrc[NB];
  char* bDst[NB];
#pragma unroll
  for (int c = 0; c < NB; c++) {
    int o = c * 256 + tid;
    int row = o >> 2, gd = o & 3;
    int gs = gd ^ ((row >> 1) & 3);
    bSrc[c] = Bt + (size_t)(n0 + row) * K + k0 + gs * 16;
    bDst[c] = smem + ABYTES + o * 16;
  }
  // ---- hoisted ds_read offsets (swizzled; loop-invariant)
  int offA[FM], offB[FN];
#pragma unroll
  for (int m = 0; m < FM; m++) {
    int row = wm + m * 16 + ln;
    offA[m] = row * 64 + ((lg ^ ((row >> 1) & 3)) << 4);
  }
#pragma unroll
  for (int n = 0; n < FN; n++) {
    int row = wn + n * 16 + ln;
    offB[n] = ABYTES + row * 64 + ((lg ^ ((row >> 1) & 3)) << 4);
  }

  auto stageStep = [&](int bufOff) {  // bufOff = 0 or BUF (compile-time)
#pragma unroll
    for (int c = 0; c < NA; c++) {
      gload_lds16(aSrc[c], aDst[c] + bufOff);
      aSrc[c] += 64;
    }
#pragma unroll
    for (int c = 0; c < NB; c++) {
      gload_lds16(bSrc[c], bDst[c] + bufOff);
      bSrc[c] += 64;
    }
  };
  auto compute = [&](int bufOff) {
    lx2 av[FM], bv[FN];
#pragma unroll
    for (int m = 0; m < FM; m++)
      av[m] = *(const lx2*)(smem + bufOff + offA[m]);
#pragma unroll
    for (int n = 0; n < FN; n++)
      bv[n] = *(const lx2*)(smem + bufOff + offB[n]);
#pragma unroll
    for (int m = 0; m < FM; m++)
#pragma unroll
      for (int n = 0; n < FN; n++)
        acc[m][n] = __builtin_amdgcn_mfma_f32_16x16x32_fp8_fp8(
            av[m][0], bv[n][0], acc[m][n], 0, 0, 0);
#pragma unroll
    for (int m = 0; m < FM; m++)
#pragma unroll
      for (int n = 0; n < FN; n++)
        acc[m][n] = __builtin_amdgcn_mfma_f32_16x16x32_fp8_fp8(
            av[m][1], bv[n][1], acc[m][n], 0, 0, 0);
  };

  stageStep(0);  // tile 0 -> buf0
  __syncthreads();
#pragma unroll 1
  for (int t = 0; t + 2 <= NTILE; t += 2) {
    stageStep(BUF);  // tile t+1 -> buf1
    compute(0);      // tile t
    __syncthreads();
    if (t + 2 < NTILE) stageStep(0);  // tile t+2 -> buf0
    compute(BUF);                     // tile t+1
    __syncthreads();
  }
  if constexpr (NTILE & 1) {  // odd tail: last tile sits in buf0
    compute(0);
    __syncthreads();
  }

  if constexpr (FUSEQ) {
    // ---- epilogue: bf16 tile + rope/FWHT/quant (padded overlay, ~free banks)
    ushort(*qtile)[132] = (ushort(*)[132])smem;
#pragma unroll
    for (int m = 0; m < FM; m++)
#pragma unroll
      for (int n = 0; n < FN; n++)
#pragma unroll
        for (int j = 0; j < 4; j++)
          qtile[wm + m * 16 + lg * 4 + j][wn + n * 16 + ln] = f2bf(acc[m][n][j]);
    __syncthreads();
    int h = blockIdx.x;  // N=8192, BN=128: one head per block column
    for (int r = 0; r < BM / 4; r++) {
      int row = wave * (BM / 4) + r;
      int tq = m0 + row;
      float v0 = bf2f(qtile[row][lane]);
      float v1 = bf2f(qtile[row][64 + lane]);
      rope_fwht_quant(v0, v1, lane, tq, cost, sint,
                      qfp8 + ((size_t)tq * NH + h) * ND,
                      qscale + (size_t)tq * NH + h);
    }
  } else {
    float* Cz = C + (size_t)blockIdx.z * M * N;
#pragma unroll
    for (int m = 0; m < FM; m++)
#pragma unroll
      for (int n = 0; n < FN; n++)
#pragma unroll
        for (int j = 0; j < 4; j++) {
          int row = m0 + wm + m * 16 + lg * 4 + j;
          int col = n0 + wn + n * 16 + ln;
          Cz[(size_t)row * N + col] = acc[m][n][j];
        }
  }
}

// ----------------------------------------------- k finalize + weights (merged)
// kpart: [KSPLIT][NT][192] f32 = 64*(hidden @ [wk|w_proj]) partials.
// LN is scale-invariant (x64 cancels); weights compensated by 0.125/64.
// Must run AFTER the fused q GEMM (needs qscale).
__global__ __launch_bounds__(256)
void kfin_weights_k(const float* __restrict__ kpart, const float* __restrict__ gamma,
                    const float* __restrict__ beta, const float* __restrict__ cost,
                    const float* __restrict__ sint, const float* __restrict__ qscale,
                    uint8_t* __restrict__ kfp8, float* __restrict__ kscale,
                    float* __restrict__ weights) {
  int l = threadIdx.x & 63;
  int row = blockIdx.x * 4 + (threadIdx.x >> 6);  // t
  float v0 = 0.0f, v1 = 0.0f, ws = 0.0f;
#pragma unroll
  for (int p = 0; p < KSPLIT; p++) {
    const float* base = kpart + (size_t)p * (NT * 192) + row * 192;
    v0 = __fadd_rn(v0, base[l]);
    v1 = __fadd_rn(v1, base[l + 64]);
    ws = __fadd_rn(ws, base[128 + l]);
  }
  // weights: * H^-0.5(=0.125) * (1/64 fp8-scale comp) * qscale * SM_SCALE
  float w = __fmul_rn(ws, 0.001953125f);
  w = __fmul_rn(w, qscale[row * NH + l]);
  w = __fmul_rn(w, 0.08838834764831843f);
  weights[row * NH + l] = w;
  // layernorm over 128
  float s = __fadd_rn(v0, v1);
#pragma unroll
  for (int m = 1; m < 64; m <<= 1) s = __fadd_rn(s, __shfl_xor(s, m, 64));
  float mu = __fmul_rn(s, 0.0078125f);
  float d0 = __fsub_rn(v0, mu), d1 = __fsub_rn(v1, mu);
  float vs = __fadd_rn(__fmul_rn(d0, d0), __fmul_rn(d1, d1));
#pragma unroll
  for (int m = 1; m < 64; m <<= 1) vs = __fadd_rn(vs, __shfl_xor(vs, m, 64));
  float var = __fmul_rn(vs, 0.0078125f);
  float rs = (float)(1.0 / sqrt((double)__fadd_rn(var, 1e-5f)));
  v0 = __fadd_rn(__fmul_rn(__fmul_rn(d0, rs), gamma[l]), beta[l]);
  v1 = __fadd_rn(__fmul_rn(__fmul_rn(d1, rs), gamma[l + 64]), beta[l + 64]);
  rope_fwht_quant(v0, v1, l, row, cost, sint, kfp8 + (size_t)row * ND, kscale + row);
}

// ------------------------------------------------------------------- scores
// Block = (4-t tile, 128-s chunk); grid 1152. Q+K staged in LDS via
// global_load_lds with a 16B-granule XOR swizzle (G ^= (row>>1)&7) so that
// ds_read_b64 fragment reads are <=2-way bank-aliased (free). Wave w covers
// s in [w*32, w*32+32) for all 64 heads; h-sum completed in-wave -> scores
// final (kscale factored out, applied in topk; exact for pow2 scales).
__global__ __launch_bounds__(256)
void scores_k(const uint8_t* __restrict__ qfp8, const uint8_t* __restrict__ kfp8,
              const float* __restrict__ weights, float* __restrict__ scores) {
  __shared__ uint8_t q_lds[TTILE * 64 * 128];  // 32KB
  __shared__ uint8_t k_lds[128 * 128];         // 16KB
  __shared__ float w_lds[TTILE * 64];          // 1KB

  int b = blockIdx.x;
  int g = 0;  // t-tile group: tiles [32g,32g+32) have g+1 s-chunks
  while (g < 7 && b >= 16 * (g + 1) * (g + 2)) g++;
  int r = b - 16 * g * (g + 1);
  int a = 32 * g + r / (g + 1);
  int chunk = r % (g + 1);
  int t0 = a * TTILE;
  int s0 = chunk * 128;

  int tid = threadIdx.x;
  int wave = tid >> 6, lane = tid & 63;
  int lg = lane >> 4, ln = lane & 15;

  // ---- stage Q (256 rows x 128B) with inverse-swizzled source, linear dest
  const uint8_t* qbase = qfp8 + (size_t)t0 * 64 * 128;
#pragma unroll
  for (int it = 0; it < 8; it++) {
    int o = it * 256 + wave * 64 + lane;  // 16B-granule index
    int row = o >> 3, G = o & 7;
    int src = row * 128 + ((G ^ ((row >> 1) & 7)) << 4);
    gload_lds16(qbase + src, q_lds + (it * 256 + wave * 64) * 16);
  }
  // ---- stage K (128 rows x 128B)
  const uint8_t* kbase = kfp8 + (size_t)s0 * 128;
#pragma unroll
  for (int it = 0; it < 4; it++) {
    int o = it * 256 + wave * 64 + lane;
    int row = o >> 3, G = o & 7;
    int src = row * 128 + ((G ^ ((row >> 1) & 7)) << 4);
    gload_lds16(kbase + src, k_lds + (it * 256 + wave * 64) * 16);
  }
  w_lds[tid] = weights[t0 * NH + tid];
  __syncthreads();

  // ---- K fragments: loaded once, reused for all 4 t and 4 h-tiles
  long bfr[2][4];
#pragma unroll
  for (int sj = 0; sj < 2; sj++) {
    int srow = wave * 32 + sj * 16 + ln;
    int base = srow * 128;
    int xr = ((srow >> 1) & 7) << 4;
#pragma unroll
    for (int ks = 0; ks < 4; ks++)
      bfr[sj][ks] = *(const long*)(k_lds + base + ((ks * 32 + lg * 8) ^ xr));
  }

  float p[TTILE][2];
#pragma unroll
  for (int tt = 0; tt < TTILE; tt++) p[tt][0] = p[tt][1] = 0.0f;

#pragma unroll
  for (int ht = 0; ht < 4; ht++) {  // head tiles of 16
    long afr[TTILE][4];
#pragma unroll
    for (int tt = 0; tt < TTILE; tt++) {
      int qrow = tt * 64 + ht * 16 + ln;
      int base = qrow * 128;
      int xr = ((qrow >> 1) & 7) << 4;
#pragma unroll
      for (int ks = 0; ks < 4; ks++)
        afr[tt][ks] = *(const long*)(q_lds + base + ((ks * 32 + lg * 8) ^ xr));
    }
#pragma unroll
    for (int tt = 0; tt < TTILE; tt++) {
      float wj[4];
#pragma unroll
      for (int j = 0; j < 4; j++) wj[j] = w_lds[tt * 64 + ht * 16 + lg * 4 + j];
#pragma unroll
      for (int sj = 0; sj < 2; sj++) {
        f32x4 acc = {0.f, 0.f, 0.f, 0.f};
#pragma unroll
        for (int ks = 0; ks < 4; ks++)
          acc = __builtin_amdgcn_mfma_f32_16x16x32_fp8_fp8(afr[tt][ks], bfr[sj][ks],
                                                           acc, 0, 0, 0);
#pragma unroll
        for (int j = 0; j < 4; j++)
          p[tt][sj] = fmaf(wj[j], fmaxf(acc[j], 0.0f), p[tt][sj]);
      }
    }
  }

#pragma unroll
  for (int tt = 0; tt < TTILE; tt++)
#pragma unroll
    for (int sj = 0; sj < 2; sj++) {
      float v = p[tt][sj];
      v += __shfl_xor(v, 16, 64);
      v += __shfl_xor(v, 32, 64);
      if (lg == 0)
        scores[(size_t)(t0 + tt) * NT + s0 + wave * 32 + sj * 16 + ln] = v;
    }
}

// -------------------------------------------------------------------- top-k
__global__ __launch_bounds__(256)
void topk_k(const float* __restrict__ scores, const float* __restrict__ kscale,
            float* __restrict__ outv, float* __restrict__ outi) {
  __shared__ unsigned long long key[1024];
  int t = blockIdx.x, tid = threadIdx.x;
#pragma unroll
  for (int p = 0; p < 4; p++) {
    int s = tid + p * 256;
    float v;
    if (s <= t) {
      v = __fmul_rn(scores[(size_t)t * NT + s], kscale[s]);  // exact pow2 factor
    } else {
      v = -1e30f;
    }
    unsigned u = __float_as_uint(v);
    unsigned ou = (u & 0x80000000u) ? ~u : (u | 0x80000000u);
    key[s] = ((unsigned long long)ou << 32) | (unsigned)(~(unsigned)s);
  }
  for (int k = 2; k <= 1024; k <<= 1) {
    for (int j = k >> 1; j > 0; j >>= 1) {
      __syncthreads();
#pragma unroll
      for (int p = 0; p < 2; p++) {
        int i = tid + p * 256;
        int l = ((i & ~(j - 1)) << 1) | (i & (j - 1));
        int m = l + j;
        bool desc = ((l & k) == 0);
        unsigned long long a = key[l], b = key[m];
        if (desc ? (a < b) : (a > b)) {
          key[l] = b;
          key[m] = a;
        }
      }
    }
  }
  __syncthreads();
#pragma unroll
  for (int p = 0; p < 2; p++) {
    int r = tid + p * 256;
    unsigned long long kk = key[r];
    unsigned ou = (unsigned)(kk >> 32);
    unsigned u = (ou & 0x80000000u) ? (ou ^ 0x80000000u) : ~ou;
    unsigned idx = (~(unsigned)(kk & 0xffffffffu)) & 1023u;
    outv[(size_t)t * NTOPK + r] = __uint_as_float(u);
    outi[(size_t)t * NTOPK + r] = (float)idx;
  }
}

// ------------------------------------------------------------------- launch
extern "C" void kernel_launch(void* const* d_in, const int* in_sizes, int n_in,
                              void* d_out, int out_size, void* d_ws, size_t ws_size,
                              hipStream_t stream) {
  const float* hidden = (const float*)d_in[0];
  const float* q_lora = (const float*)d_in[1];
  const int* positions = (const int*)d_in[2];
  const float* wq_b = (const float*)d_in[3];
  const float* wk = (const float*)d_in[4];
  const float* w_proj = (const float*)d_in[5];
  const float* ln_g = (const float*)d_in[6];
  const float* ln_b = (const float*)d_in[7];
  float* out = (float*)d_out;

  // ---- workspace layout (all fp8 operands coexist; scores aliases hidden8)
  char* u0 = (char*)d_ws;
  uint8_t* hidden8 = (uint8_t*)u0;                     //  7,340,032 B
  uint8_t* wkp8 = (uint8_t*)(u0 + 7340032);            //  1,376,256 B
  uint8_t* wqb8 = (uint8_t*)(u0 + 8716288);            // 12,582,912 B
  uint8_t* qlora8 = (uint8_t*)(u0 + 21299200);         //  1,572,864 B
  float* scores = (float*)u0;  // 4,194,304 B; hidden8 dead before scores_k
  char* p = u0 + 22872064;
  float* kpart = (float*)p;    p += 12582912;          // [16][1024][192] f32
  float* cost = (float*)p;     p += 131072;
  float* sint = (float*)p;     p += 131072;
  float* kscale = (float*)p;   p += 4096;
  float* qscale = (float*)p;   p += 262144;
  float* weights = (float*)p;  p += 262144;
  uint8_t* kfp8 = (uint8_t*)p; p += 131072;
  uint8_t* qfp8 = (uint8_t*)p; p += 8388608;

  // 1) all casts + rope table (kk-interleaved fp8 outputs)
  prep_all_k<<<7760, 256, 0, stream>>>(hidden, q_lora, wk, w_proj, wq_b,
                                       positions, (uint32_t*)hidden8,
                                       (uint32_t*)qlora8, wkp8, wqb8,
                                       cost, sint);

  // 2) k + weights projections (B = [wk|w_proj] x64; LN scale-invariant,
  //    weights compensated by 1/64 in kfin_weights_k). KCHUNK=448 -> 7 iters.
  gemm_fp8_k<64, 64, 448, false><<<dim3(3, 16, KSPLIT), 256, 0, stream>>>(
      hidden8, wkp8, kpart, nullptr, nullptr, nullptr, nullptr,
      NT, 192, NHID);

  // 3) q projection with fused rope/FWHT/quant epilogue (24 iters)
  gemm_fp8_k<64, 128, 1536, true><<<dim3(64, 16, 1), 256, 0, stream>>>(
      qlora8, wqb8, nullptr, cost, sint, qfp8, qscale,
      NT, NH * ND, NR);

  // 4) k finalize + weights
  kfin_weights_k<<<NT / 4, 256, 0, stream>>>(kpart, ln_g, ln_b, cost, sint,
                                             qscale, kfp8, kscale, weights);

  // 5) scores + 6) top-k
  scores_k<<<1152, 256, 0, stream>>>(qfp8, kfp8, weights, scores);
  topk_k<<<NT, 256, 0, stream>>>(scores, kscale, out, out + (size_t)NT * NTOPK);
}

// Round 17
// 107.329 us; speedup vs baseline: 1.0909x; 1.0744x over previous
//
#include <hip/hip_runtime.h>
#include <cstdint>
#include <cmath>

// Problem constants (T=1024, HID=7168, R=1536, H=64, D=128, RD=64, TOPK=512)
#define NT 1024
#define NHID 7168
#define NR 1536
#define NH 64
#define ND 128
#define NTOPK 512
#define TTILE 4
#define KSPLIT 8

typedef float f32x4 __attribute__((ext_vector_type(4)));
typedef long lx2 __attribute__((ext_vector_type(2)));

__device__ __forceinline__ ushort f2bf(float x) {  // RNE f32->bf16
  uint32_t u = __float_as_uint(x);
  u += 0x7fffu + ((u >> 16) & 1u);
  return (ushort)(u >> 16);
}
__device__ __forceinline__ float bf2f(ushort u) {
  return __uint_as_float(((uint32_t)u) << 16);
}
__device__ __forceinline__ void gload_lds16(const void* g, void* l) {
  __builtin_amdgcn_global_load_lds(
      (const __attribute__((address_space(1))) uint32_t*)g,
      (__attribute__((address_space(3))) uint32_t*)l, 16, 0, 0);
}
__device__ __forceinline__ uint32_t pk_fp8x4(float a, float b, float c, float d) {
  uint32_t lo = (uint32_t)__builtin_amdgcn_cvt_pk_fp8_f32(a, b, 0, false) & 0xffffu;
  uint32_t hi = (uint32_t)__builtin_amdgcn_cvt_pk_fp8_f32(c, d, 0, false) << 16;
  return lo | hi;
}

// kk-interleaved GLOBAL layout (r12): within each 64B K-block, byte k
// (kk=k>>5, lg=(k>>3)&3, b=k&7) lives at lg*16 + kk*8 + b, so granule g
// holds the (kk0,kk1) fragment pair for lg=g (one ds_read_b128 -> 2 frags).
// LDS swizzle (r14): slot_phys = lg ^ ((row>>1)&3) -> conflict-free (262K).
// r17: q GEMM (1024 blocks) + kw GEMM (384 blocks, KSPLIT=8) fused into ONE
// 1408-block launch via block-range dispatch -> 5.5 blocks/CU of independent
// waves (r14's q grid capped occupancy at 4/CU; LDS 24KB allows 6/CU).

// ---------------------------------------------------------- rope+fwht+quant
// One wave per 128-elem row: lane l owns elements l and l+64.
__device__ __forceinline__ void rope_fwht_quant(
    float v0, float v1, int l, int pos_t,
    const float* __restrict__ cost, const float* __restrict__ sint,
    uint8_t* __restrict__ out_bytes, float* __restrict__ out_scale) {
  float a = __shfl(v0, (2 * l) & 63, 64);      // x[2i]
  float b = __shfl(v0, (2 * l + 1) & 63, 64);  // x[2i+1]
  int fi = l & 31;
  float c = cost[pos_t * 32 + fi];
  float sn = sint[pos_t * 32 + fi];
  float r;
  if (l < 32)
    r = __fsub_rn(__fmul_rn(a, c), __fmul_rn(b, sn));
  else
    r = __fadd_rn(__fmul_rn(b, c), __fmul_rn(a, sn));
  v0 = r;  // elements 64..127 untouched by rope

#pragma unroll
  for (int m = 1; m < 64; m <<= 1) {  // FWHT Sylvester order
    float p0 = __shfl_xor(v0, m, 64);
    float p1 = __shfl_xor(v1, m, 64);
    bool up = (l & m) == 0;
    v0 = up ? __fadd_rn(v0, p0) : __fsub_rn(p0, v0);
    v1 = up ? __fadd_rn(v1, p1) : __fsub_rn(p1, v1);
  }
  {  // m = 64: pair (l, l+64) lane-local
    float A0 = v0, B0 = v1;
    v0 = __fadd_rn(A0, B0);
    v1 = __fsub_rn(A0, B0);
  }
  const float WS = 0.08838834764831843f;  // 128^-0.5
  v0 = __fmul_rn(v0, WS);
  v1 = __fmul_rn(v1, WS);

  float am = fmaxf(fabsf(v0), fabsf(v1));
#pragma unroll
  for (int m = 1; m < 64; m <<= 1) am = fmaxf(am, __shfl_xor(am, m, 64));
  am = fmaxf(am, 1e-4f);
  float ratio = __fdiv_rn(am, 448.0f);
  // exact ceil(log2(ratio)) via mantissa carry (UE8M0)
  uint32_t rb = __float_as_uint(ratio);
  int e = (int)((rb + 0x7fffffu) >> 23) - 127;
  float sf = __uint_as_float((uint32_t)(e + 127) << 23);
  float inv = __uint_as_float((uint32_t)(127 - e) << 23);
  float q0 = __fmul_rn(v0, inv);
  float q1 = __fmul_rn(v1, inv);
  int b0 = __builtin_amdgcn_cvt_pk_fp8_f32(q0, q0, 0, false);
  int b1 = __builtin_amdgcn_cvt_pk_fp8_f32(q1, q1, 0, false);
  out_bytes[l] = (uint8_t)(b0 & 0xff);
  out_bytes[l + 64] = (uint8_t)(b1 & 0xff);
  if (l == 0) *out_scale = sf;
}

// --------------------- prep: rope table + all fp8 casts/transposes (1 launch)
// Blocks [0,3584): hidden cast (+rope table in [0,1024));
// [3584,4352): q_lora cast; [4352,4688): wk/w_proj transpose-cast (x64);
// [4688,7760): wq_b transpose-cast. All outputs kk-interleaved.
__global__ __launch_bounds__(256)
void prep_all_k(const float* __restrict__ hidden, const float* __restrict__ q_lora,
                const float* __restrict__ wk, const float* __restrict__ wp,
                const float* __restrict__ wq_b, const int* __restrict__ pos,
                uint32_t* __restrict__ hidden8, uint32_t* __restrict__ qlora8,
                uint8_t* __restrict__ wkp8, uint8_t* __restrict__ wqb8,
                float* __restrict__ cost, float* __restrict__ sint) {
  __shared__ uint8_t t8[64][68];
  int bid = blockIdx.x, tid = threadIdx.x;
  if (bid < 4352) {
    // ---- linear casts, 8 f32 -> one permuted 8B group
    bool isq = bid >= 3584;
    size_t i = (size_t)(isq ? bid - 3584 : bid) * 256 + tid;
    const float* src = isq ? q_lora : hidden;
    uint32_t* dst = isq ? qlora8 : hidden8;
    const f32x4* pp = (const f32x4*)(src + i * 8);
    f32x4 a = pp[0], b = pp[1];
    size_t blk = i >> 3;
    int j = (int)(i & 7);
    size_t dw = blk * 16 + (size_t)((j & 3) * 4 + (j >> 2) * 2);
    dst[dw] = pk_fp8x4(a[0], a[1], a[2], a[3]);
    dst[dw + 1] = pk_fp8x4(b[0], b[1], b[2], b[3]);
    if (bid < NT && tid < 32) {
      int t = bid, ii = tid;
      double x = (double)(2 * ii) / 64.0;
      double pw = pow(10000.0, x);
      float p32 = (float)pw;
      float invf = __fdiv_rn(1.0f, p32);
      float ang = __fmul_rn((float)pos[t], invf);
      cost[t * 32 + ii] = (float)cos((double)ang);
      sint[t * 32 + ii] = (float)sin((double)ang);
    }
    return;
  }
  // ---- transpose-cast: in [K][N_] f32 -> out [N_row][Kdim] e4m3 interleaved
  const float* in;
  uint8_t* out;
  int N_, n0, orow0, Kdim, k0;
  float scale;
  if (bid < 4688) {
    int local = bid - 4352;
    int bx = local % 3, by = local / 3;
    in = (bx < 2) ? wk : wp;
    N_ = (bx < 2) ? ND : NH;
    n0 = (bx < 2) ? bx * 64 : 0;
    orow0 = (bx < 2) ? bx * 64 : 128;
    Kdim = NHID;
    k0 = by * 64;
    out = wkp8;
    scale = 64.0f;
  } else {
    int local = bid - 4688;
    int nx = local % 128, ky = local / 128;
    in = wq_b;
    N_ = NH * ND;
    n0 = nx * 64;
    orow0 = n0;
    Kdim = NR;
    k0 = ky * 64;
    out = wqb8;
    scale = 1.0f;
  }
  int r = tid >> 4, c = (tid & 15) * 4;
#pragma unroll
  for (int rr = 0; rr < 64; rr += 16) {
    f32x4 v = *(const f32x4*)(in + (size_t)(k0 + rr + r) * N_ + n0 + c);
    *(uint32_t*)&t8[rr + r][c] =
        pk_fp8x4(v[0] * scale, v[1] * scale, v[2] * scale, v[3] * scale);
  }
  __syncthreads();
  int sp = ((c >> 3) & 3) * 16 + (c >> 5) * 8 + ((c >> 2) & 1) * 4;  // kk-perm
#pragma unroll
  for (int rr = 0; rr < 64; rr += 16) {
    int orow = rr + r;
    uint32_t w = (uint32_t)t8[c + 0][orow] | ((uint32_t)t8[c + 1][orow] << 8) |
                 ((uint32_t)t8[c + 2][orow] << 16) | ((uint32_t)t8[c + 3][orow] << 24);
    *(uint32_t*)(out + (size_t)(orow0 + orow) * Kdim + k0 + sp) = w;
  }
}

// --------------- fp8 GEMM body (r14-exact 2-phase loop; called per block-path)
// 4 waves (2x2), wave tile (BM/2)x(BN/2), BK=64, dbuf. Loop: stage(0); sync;
// { stage(t+1); compute(t); sync; }. One b128 at slot lg^((row>>1)&3) yields
// the (kk0,kk1) fragment pair; per-phase bank load exactly 2 dwords (free).
// FUSEQ: BN=128 block column = one head; epilogue = bf16 tile in padded LDS
// overlay + rope/FWHT/quant. Else: f32 partials C[bz*M*N + m*N + n].
template <int BM, int BN, bool FUSEQ>
__device__ __forceinline__
void gemm_body(char* smem, const uint8_t* __restrict__ A,
               const uint8_t* __restrict__ Bt, float* __restrict__ C,
               const float* __restrict__ cost, const float* __restrict__ sint,
               uint8_t* __restrict__ qfp8, float* __restrict__ qscale,
               int M, int N, int K, int kchunk, int bx, int by, int bz) {
  constexpr int FM = BM / 32;
  constexpr int FN = BN / 32;
  constexpr int ABYTES = BM * 64;
  constexpr int BBYTES = BN * 64;
  constexpr int BUF = ABYTES + BBYTES;
  int tid = threadIdx.x;
  int wave = tid >> 6, lane = tid & 63;
  int ln = lane & 15, lg = lane >> 4;
  int n0 = bx * BN, m0 = by * BM;
  int k0 = bz * kchunk;
  int wm = (wave >> 1) * (BM / 2), wn = (wave & 1) * (BN / 2);

  f32x4 acc[FM][FN];
#pragma unroll
  for (int m = 0; m < FM; m++)
#pragma unroll
    for (int n = 0; n < FN; n++) acc[m][n] = {0.f, 0.f, 0.f, 0.f};

  auto stage = [&](int buf, int kk0) {
    char* base = smem + buf * BUF;
#pragma unroll
    for (int c = 0; c < BM / 64; c++) {  // A: BM rows x 64B, swizzled src
      int o = c * 256 + tid;
      int row = o >> 2, gd = o & 3;
      int gs = gd ^ ((row >> 1) & 3);
      gload_lds16(A + (size_t)(m0 + row) * K + kk0 + gs * 16, base + o * 16);
    }
#pragma unroll
    for (int c = 0; c < BN / 64; c++) {  // B: BN rows x 64B, swizzled src
      int o = c * 256 + tid;
      int row = o >> 2, gd = o & 3;
      int gs = gd ^ ((row >> 1) & 3);
      gload_lds16(Bt + (size_t)(n0 + row) * K + kk0 + gs * 16,
                  base + ABYTES + o * 16);
    }
  };

  int ntile = kchunk / 64;
  stage(0, k0);
  __syncthreads();
  int cur = 0;
  for (int t = 0; t < ntile; t++) {
    if (t + 1 < ntile) stage(cur ^ 1, k0 + (t + 1) * 64);
    const uint8_t* ap = (const uint8_t*)smem + cur * BUF;
    const uint8_t* bp = ap + ABYTES;
    lx2 av[FM], bv[FN];
#pragma unroll
    for (int m = 0; m < FM; m++) {
      int row = wm + m * 16 + ln;
      av[m] = *(const lx2*)(ap + row * 64 + ((lg ^ ((row >> 1) & 3)) << 4));
    }
#pragma unroll
    for (int n = 0; n < FN; n++) {
      int row = wn + n * 16 + ln;
      bv[n] = *(const lx2*)(bp + row * 64 + ((lg ^ ((row >> 1) & 3)) << 4));
    }
#pragma unroll
    for (int m = 0; m < FM; m++)
#pragma unroll
      for (int n = 0; n < FN; n++)
        acc[m][n] = __builtin_amdgcn_mfma_f32_16x16x32_fp8_fp8(
            av[m][0], bv[n][0], acc[m][n], 0, 0, 0);
#pragma unroll
    for (int m = 0; m < FM; m++)
#pragma unroll
      for (int n = 0; n < FN; n++)
        acc[m][n] = __builtin_amdgcn_mfma_f32_16x16x32_fp8_fp8(
            av[m][1], bv[n][1], acc[m][n], 0, 0, 0);
    __syncthreads();
    cur ^= 1;
  }

  if constexpr (FUSEQ) {
    // ---- epilogue: bf16 tile + rope/FWHT/quant (padded overlay, ~free banks)
    ushort(*qtile)[132] = (ushort(*)[132])smem;
#pragma unroll
    for (int m = 0; m < FM; m++)
#pragma unroll
      for (int n = 0; n < FN; n++)
#pragma unroll
        for (int j = 0; j < 4; j++)
          qtile[wm + m * 16 + lg * 4 + j][wn + n * 16 + ln] = f2bf(acc[m][n][j]);
    __syncthreads();
    int h = bx;  // N=8192, BN=128: one head per block column
    for (int r = 0; r < BM / 4; r++) {
      int row = wave * (BM / 4) + r;
      int tq = m0 + row;
      float v0 = bf2f(qtile[row][lane]);
      float v1 = bf2f(qtile[row][64 + lane]);
      rope_fwht_quant(v0, v1, lane, tq, cost, sint,
                      qfp8 + ((size_t)tq * NH + h) * ND,
                      qscale + (size_t)tq * NH + h);
    }
  } else {
    float* Cz = C + (size_t)bz * M * N;
#pragma unroll
    for (int m = 0; m < FM; m++)
#pragma unroll
      for (int n = 0; n < FN; n++)
#pragma unroll
        for (int j = 0; j < 4; j++) {
          int row = m0 + wm + m * 16 + lg * 4 + j;
          int col = n0 + wn + n * 16 + ln;
          Cz[(size_t)row * N + col] = acc[m][n][j];
        }
  }
}

// ------------------- fused GEMM dispatch: [0,1024)=q, [1024,1408)=kw
__global__ __launch_bounds__(256)
void gemm_all_k(const uint8_t* __restrict__ qlora8, const uint8_t* __restrict__ wqb8,
                const uint8_t* __restrict__ hidden8, const uint8_t* __restrict__ wkp8,
                float* __restrict__ kpart, const float* __restrict__ cost,
                const float* __restrict__ sint, uint8_t* __restrict__ qfp8,
                float* __restrict__ qscale) {
  __shared__ char smem[24576];  // max(q: 2*12288, kw: 2*8192, overlay 16896)
  int bid = blockIdx.x;
  if (bid < 1024) {
    // q projection with fused rope/FWHT/quant; grid (64 n-blocks x 16 m-blocks)
    gemm_body<64, 128, true>(smem, qlora8, wqb8, nullptr, cost, sint, qfp8,
                             qscale, NT, NH * ND, NR, NR,
                             bid & 63, bid >> 6, 0);
  } else {
    // kw projections: grid (3 n x 16 m x 8 z), kchunk = 896 (14 iters)
    int kb = bid - 1024;
    gemm_body<64, 64, false>(smem, hidden8, wkp8, kpart, nullptr, nullptr,
                             nullptr, nullptr, NT, 192, NHID, NHID / KSPLIT,
                             kb % 3, (kb / 3) & 15, kb / 48);
  }
}

// ----------------------------------------------- k finalize + weights (merged)
// kpart: [KSPLIT][NT][192] f32 = 64*(hidden @ [wk|w_proj]) partials.
// LN is scale-invariant (x64 cancels); weights compensated by 0.125/64.
// Must run AFTER the fused GEMM launch (needs qscale + kpart).
__global__ __launch_bounds__(256)
void kfin_weights_k(const float* __restrict__ kpart, const float* __restrict__ gamma,
                    const float* __restrict__ beta, const float* __restrict__ cost,
                    const float* __restrict__ sint, const float* __restrict__ qscale,
                    uint8_t* __restrict__ kfp8, float* __restrict__ kscale,
                    float* __restrict__ weights) {
  int l = threadIdx.x & 63;
  int row = blockIdx.x * 4 + (threadIdx.x >> 6);  // t
  float v0 = 0.0f, v1 = 0.0f, ws = 0.0f;
#pragma unroll
  for (int p = 0; p < KSPLIT; p++) {
    const float* base = kpart + (size_t)p * (NT * 192) + row * 192;
    v0 = __fadd_rn(v0, base[l]);
    v1 = __fadd_rn(v1, base[l + 64]);
    ws = __fadd_rn(ws, base[128 + l]);
  }
  // weights: * H^-0.5(=0.125) * (1/64 fp8-scale comp) * qscale * SM_SCALE
  float w = __fmul_rn(ws, 0.001953125f);
  w = __fmul_rn(w, qscale[row * NH + l]);
  w = __fmul_rn(w, 0.08838834764831843f);
  weights[row * NH + l] = w;
  // layernorm over 128
  float s = __fadd_rn(v0, v1);
#pragma unroll
  for (int m = 1; m < 64; m <<= 1) s = __fadd_rn(s, __shfl_xor(s, m, 64));
  float mu = __fmul_rn(s, 0.0078125f);
  float d0 = __fsub_rn(v0, mu), d1 = __fsub_rn(v1, mu);
  float vs = __fadd_rn(__fmul_rn(d0, d0), __fmul_rn(d1, d1));
#pragma unroll
  for (int m = 1; m < 64; m <<= 1) vs = __fadd_rn(vs, __shfl_xor(vs, m, 64));
  float var = __fmul_rn(vs, 0.0078125f);
  float rs = (float)(1.0 / sqrt((double)__fadd_rn(var, 1e-5f)));
  v0 = __fadd_rn(__fmul_rn(__fmul_rn(d0, rs), gamma[l]), beta[l]);
  v1 = __fadd_rn(__fmul_rn(__fmul_rn(d1, rs), gamma[l + 64]), beta[l + 64]);
  rope_fwht_quant(v0, v1, l, row, cost, sint, kfp8 + (size_t)row * ND, kscale + row);
}

// ------------------------------------------------------------------- scores
// Block = (4-t tile, 128-s chunk); grid 1152. Q+K staged in LDS via
// global_load_lds with a 16B-granule XOR swizzle (G ^= (row>>1)&7) so that
// ds_read_b64 fragment reads are <=2-way bank-aliased (free). Wave w covers
// s in [w*32, w*32+32) for all 64 heads; h-sum completed in-wave -> scores
// final (kscale factored out, applied in topk; exact for pow2 scales).
__global__ __launch_bounds__(256)
void scores_k(const uint8_t* __restrict__ qfp8, const uint8_t* __restrict__ kfp8,
              const float* __restrict__ weights, float* __restrict__ scores) {
  __shared__ uint8_t q_lds[TTILE * 64 * 128];  // 32KB
  __shared__ uint8_t k_lds[128 * 128];         // 16KB
  __shared__ float w_lds[TTILE * 64];          // 1KB

  int b = blockIdx.x;
  int g = 0;  // t-tile group: tiles [32g,32g+32) have g+1 s-chunks
  while (g < 7 && b >= 16 * (g + 1) * (g + 2)) g++;
  int r = b - 16 * g * (g + 1);
  int a = 32 * g + r / (g + 1);
  int chunk = r % (g + 1);
  int t0 = a * TTILE;
  int s0 = chunk * 128;

  int tid = threadIdx.x;
  int wave = tid >> 6, lane = tid & 63;
  int lg = lane >> 4, ln = lane & 15;

  // ---- stage Q (256 rows x 128B) with inverse-swizzled source, linear dest
  const uint8_t* qbase = qfp8 + (size_t)t0 * 64 * 128;
#pragma unroll
  for (int it = 0; it < 8; it++) {
    int o = it * 256 + wave * 64 + lane;  // 16B-granule index
    int row = o >> 3, G = o & 7;
    int src = row * 128 + ((G ^ ((row >> 1) & 7)) << 4);
    gload_lds16(qbase + src, q_lds + (it * 256 + wave * 64) * 16);
  }
  // ---- stage K (128 rows x 128B)
  const uint8_t* kbase = kfp8 + (size_t)s0 * 128;
#pragma unroll
  for (int it = 0; it < 4; it++) {
    int o = it * 256 + wave * 64 + lane;
    int row = o >> 3, G = o & 7;
    int src = row * 128 + ((G ^ ((row >> 1) & 7)) << 4);
    gload_lds16(kbase + src, k_lds + (it * 256 + wave * 64) * 16);
  }
  w_lds[tid] = weights[t0 * NH + tid];
  __syncthreads();

  // ---- K fragments: loaded once, reused for all 4 t and 4 h-tiles
  long bfr[2][4];
#pragma unroll
  for (int sj = 0; sj < 2; sj++) {
    int srow = wave * 32 + sj * 16 + ln;
    int base = srow * 128;
    int xr = ((srow >> 1) & 7) << 4;
#pragma unroll
    for (int ks = 0; ks < 4; ks++)
      bfr[sj][ks] = *(const long*)(k_lds + base + ((ks * 32 + lg * 8) ^ xr));
  }

  float p[TTILE][2];
#pragma unroll
  for (int tt = 0; tt < TTILE; tt++) p[tt][0] = p[tt][1] = 0.0f;

#pragma unroll
  for (int ht = 0; ht < 4; ht++) {  // head tiles of 16
    long afr[TTILE][4];
#pragma unroll
    for (int tt = 0; tt < TTILE; tt++) {
      int qrow = tt * 64 + ht * 16 + ln;
      int base = qrow * 128;
      int xr = ((qrow >> 1) & 7) << 4;
#pragma unroll
      for (int ks = 0; ks < 4; ks++)
        afr[tt][ks] = *(const long*)(q_lds + base + ((ks * 32 + lg * 8) ^ xr));
    }
#pragma unroll
    for (int tt = 0; tt < TTILE; tt++) {
      float wj[4];
#pragma unroll
      for (int j = 0; j < 4; j++) wj[j] = w_lds[tt * 64 + ht * 16 + lg * 4 + j];
#pragma unroll
      for (int sj = 0; sj < 2; sj++) {
        f32x4 acc = {0.f, 0.f, 0.f, 0.f};
#pragma unroll
        for (int ks = 0; ks < 4; ks++)
          acc = __builtin_amdgcn_mfma_f32_16x16x32_fp8_fp8(afr[tt][ks], bfr[sj][ks],
                                                           acc, 0, 0, 0);
#pragma unroll
        for (int j = 0; j < 4; j++)
          p[tt][sj] = fmaf(wj[j], fmaxf(acc[j], 0.0f), p[tt][sj]);
      }
    }
  }

#pragma unroll
  for (int tt = 0; tt < TTILE; tt++)
#pragma unroll
    for (int sj = 0; sj < 2; sj++) {
      float v = p[tt][sj];
      v += __shfl_xor(v, 16, 64);
      v += __shfl_xor(v, 32, 64);
      if (lg == 0)
        scores[(size_t)(t0 + tt) * NT + s0 + wave * 32 + sj * 16 + ln] = v;
    }
}

// -------------------------------------------------------------------- top-k
__global__ __launch_bounds__(256)
void topk_k(const float* __restrict__ scores, const float* __restrict__ kscale,
            float* __restrict__ outv, float* __restrict__ outi) {
  __shared__ unsigned long long key[1024];
  int t = blockIdx.x, tid = threadIdx.x;
#pragma unroll
  for (int p = 0; p < 4; p++) {
    int s = tid + p * 256;
    float v;
    if (s <= t) {
      v = __fmul_rn(scores[(size_t)t * NT + s], kscale[s]);  // exact pow2 factor
    } else {
      v = -1e30f;
    }
    unsigned u = __float_as_uint(v);
    unsigned ou = (u & 0x80000000u) ? ~u : (u | 0x80000000u);
    key[s] = ((unsigned long long)ou << 32) | (unsigned)(~(unsigned)s);
  }
  for (int k = 2; k <= 1024; k <<= 1) {
    for (int j = k >> 1; j > 0; j >>= 1) {
      __syncthreads();
#pragma unroll
      for (int p = 0; p < 2; p++) {
        int i = tid + p * 256;
        int l = ((i & ~(j - 1)) << 1) | (i & (j - 1));
        int m = l + j;
        bool desc = ((l & k) == 0);
        unsigned long long a = key[l], b = key[m];
        if (desc ? (a < b) : (a > b)) {
          key[l] = b;
          key[m] = a;
        }
      }
    }
  }
  __syncthreads();
#pragma unroll
  for (int p = 0; p < 2; p++) {
    int r = tid + p * 256;
    unsigned long long kk = key[r];
    unsigned ou = (unsigned)(kk >> 32);
    unsigned u = (ou & 0x80000000u) ? (ou ^ 0x80000000u) : ~ou;
    unsigned idx = (~(unsigned)(kk & 0xffffffffu)) & 1023u;
    outv[(size_t)t * NTOPK + r] = __uint_as_float(u);
    outi[(size_t)t * NTOPK + r] = (float)idx;
  }
}

// ------------------------------------------------------------------- launch
extern "C" void kernel_launch(void* const* d_in, const int* in_sizes, int n_in,
                              void* d_out, int out_size, void* d_ws, size_t ws_size,
                              hipStream_t stream) {
  const float* hidden = (const float*)d_in[0];
  const float* q_lora = (const float*)d_in[1];
  const int* positions = (const int*)d_in[2];
  const float* wq_b = (const float*)d_in[3];
  const float* wk = (const float*)d_in[4];
  const float* w_proj = (const float*)d_in[5];
  const float* ln_g = (const float*)d_in[6];
  const float* ln_b = (const float*)d_in[7];
  float* out = (float*)d_out;

  // ---- workspace layout (all fp8 operands coexist; scores aliases hidden8)
  char* u0 = (char*)d_ws;
  uint8_t* hidden8 = (uint8_t*)u0;                     //  7,340,032 B
  uint8_t* wkp8 = (uint8_t*)(u0 + 7340032);            //  1,376,256 B
  uint8_t* wqb8 = (uint8_t*)(u0 + 8716288);            // 12,582,912 B
  uint8_t* qlora8 = (uint8_t*)(u0 + 21299200);         //  1,572,864 B
  float* scores = (float*)u0;  // 4,194,304 B; hidden8 dead before scores_k
  char* p = u0 + 22872064;
  float* kpart = (float*)p;    p += 6291456;           // [8][1024][192] f32
  float* cost = (float*)p;     p += 131072;
  float* sint = (float*)p;     p += 131072;
  float* kscale = (float*)p;   p += 4096;
  float* qscale = (float*)p;   p += 262144;
  float* weights = (float*)p;  p += 262144;
  uint8_t* kfp8 = (uint8_t*)p; p += 131072;
  uint8_t* qfp8 = (uint8_t*)p; p += 8388608;

  // 1) all casts + rope table (kk-interleaved fp8 outputs)
  prep_all_k<<<7760, 256, 0, stream>>>(hidden, q_lora, wk, w_proj, wq_b,
                                       positions, (uint32_t*)hidden8,
                                       (uint32_t*)qlora8, wkp8, wqb8,
                                       cost, sint);

  // 2) fused q GEMM (+rope/FWHT/quant) and kw GEMM in one 1408-block launch
  gemm_all_k<<<1408, 256, 0, stream>>>(qlora8, wqb8, hidden8, wkp8, kpart,
                                       cost, sint, qfp8, qscale);

  // 3) k finalize + weights
  kfin_weights_k<<<NT / 4, 256, 0, stream>>>(kpart, ln_g, ln_b, cost, sint,
                                             qscale, kfp8, kscale, weights);

  // 4) scores + 5) top-k
  scores_k<<<1152, 256, 0, stream>>>(qfp8, kfp8, weights, scores);
  topk_k<<<NT, 256, 0, stream>>>(scores, kscale, out, out + (size_t)NT * NTOPK);
}